// Round 4
// baseline (828.878 us; speedup 1.0000x reference)
//
#include <hip/hip_runtime.h>
#include <hip/hip_bf16.h>
#include <math.h>

// Swin block: LN1 -> shift+window -> QKV -> MFMA attn -> proj(+reverse+res)
//             -> LN2 -> FUSED MLP (fc1+GELU+fc2+res, h never touches HBM)
// R4: fused_mlp occupancy fix (no LDS A-slab, 33.4 KB LDS, 3 waves/EU cap);
//     gemm_bt n-major block swizzle for A-tile L2 reuse.

typedef __bf16 bf16_t;
typedef __bf16 bf16x4 __attribute__((ext_vector_type(4)));
typedef __bf16 bf16x8 __attribute__((ext_vector_type(8)));
typedef float f32x4 __attribute__((ext_vector_type(4)));

#define AS1 __attribute__((address_space(1)))
#define AS3 __attribute__((address_space(3)))

__device__ __forceinline__ void gload_lds16(const bf16_t* g, bf16_t* l) {
  __builtin_amdgcn_global_load_lds((AS1 void*)g, (AS3 void*)l, 16, 0, 0);
}

// ---------------- weight transpose + cast (3 K=256 weights in one grid) ---
__global__ void transpose_cast3(const float* __restrict__ qkv_w,
                                const float* __restrict__ proj_w,
                                const float* __restrict__ fc1_w,
                                bf16_t* __restrict__ qkvWt,
                                bf16_t* __restrict__ projWt,
                                bf16_t* __restrict__ fc1Wt) {
  int idx = blockIdx.x * 256 + threadIdx.x;
  const float* w;
  bf16_t* wt;
  int N;
  if (blockIdx.y == 0) { w = qkv_w; wt = qkvWt; N = 768; }
  else if (blockIdx.y == 1) { w = proj_w; wt = projWt; N = 256; }
  else { w = fc1_w; wt = fc1Wt; N = 1024; }
  if (idx < N * 256) {
    int n = idx >> 8, k = idx & 255;
    wt[idx] = (bf16_t)w[(size_t)k * N + n];
  }
}

__global__ void transpose_cast(const float* __restrict__ w, bf16_t* __restrict__ wt,
                               int K, int N) {
  int idx = blockIdx.x * 256 + threadIdx.x;
  if (idx < N * K) {
    int n = idx / K, k = idx - n * K;
    wt[idx] = (bf16_t)w[(size_t)k * N + n];
  }
}

// ---------------- bias+mask table: bm[type][head][64][64] fp32 -----------
__global__ void build_bm(const float* __restrict__ rpb, float* __restrict__ bm) {
  int t = blockIdx.x, h = blockIdx.y;
  int wr = (t & 2) ? 7 : 0, wc = (t & 1) ? 7 : 0;
  for (int e = threadIdx.x; e < 4096; e += 256) {
    int r = e >> 6, c = e & 63;
    float v;
    if (c >= 49) {
      v = -30000.f;
    } else if (r >= 49) {
      v = 0.f;
    } else {
      int r1 = r / 7, c1 = r - r1 * 7;
      int r2 = c / 7, c2 = c - r2 * 7;
      v = rpb[((r1 - r2 + 6) * 13 + (c1 - c2 + 6)) * 8 + h];
      int hp = wr * 7 + r1, wp = wc * 7 + c1;
      int hq = wr * 7 + r2, wq = wc * 7 + c2;
      int ri = (hp < 49 ? 0 : (hp < 53 ? 1 : 2)) * 3 + (wp < 49 ? 0 : (wp < 53 ? 1 : 2));
      int rj = (hq < 49 ? 0 : (hq < 53 ? 1 : 2)) * 3 + (wq < 49 ? 0 : (wq < 53 ? 1 : 2));
      if (ri != rj) v -= 100.f;
    }
    bm[((size_t)(t * 8 + h) * 64 + r) * 64 + c] = v;
  }
}

// ---------------- LayerNorm (+ optional shift/window gather) -> bf16 ------
__global__ __launch_bounds__(256)
void ln_cast(const float* __restrict__ src, const float* __restrict__ gamma,
             const float* __restrict__ beta, bf16_t* __restrict__ dst, int windowed) {
  int row = blockIdx.x * 4 + (threadIdx.x >> 6);
  int lane = threadIdx.x & 63;
  size_t srow;
  if (windowed) {
    int w = row / 49, t = row - w * 49;
    int img = w >> 6, wi = w & 63;
    int wr = wi >> 3, wc = wi & 7;
    int rr = t / 7, cc = t - rr * 7;
    int h = wr * 7 + rr + 3; if (h >= 56) h -= 56;
    int ww = wc * 7 + cc + 3; if (ww >= 56) ww -= 56;
    srow = (size_t)img * 3136 + h * 56 + ww;
  } else {
    srow = row;
  }
  float4 v = *(const float4*)(src + srow * 256 + lane * 4);
  float s = v.x + v.y + v.z + v.w;
  float s2 = v.x * v.x + v.y * v.y + v.z * v.z + v.w * v.w;
#pragma unroll
  for (int off = 32; off > 0; off >>= 1) {
    s += __shfl_xor(s, off);
    s2 += __shfl_xor(s2, off);
  }
  float mu = s * (1.0f / 256.0f);
  float rs = rsqrtf(s2 * (1.0f / 256.0f) - mu * mu + 1e-5f);
  float4 g = *(const float4*)(gamma + lane * 4);
  float4 b = *(const float4*)(beta + lane * 4);
  bf16x4 o;
  o[0] = (bf16_t)((v.x - mu) * rs * g.x + b.x);
  o[1] = (bf16_t)((v.y - mu) * rs * g.y + b.y);
  o[2] = (bf16_t)((v.z - mu) * rs * g.z + b.z);
  o[3] = (bf16_t)((v.w - mu) * rs * g.w + b.w);
  *(bf16x4*)(dst + (size_t)row * 256 + lane * 4) = o;
}

// ---------------- GEMM: C[M,N] = A[M,K] * Bt[N,K]^T -----------------------
// 1-D grid, n-major within m: consecutive blocks share the A-tile (L2 reuse).
// MODE 0: +bias -> bf16 (QKV)   MODE 3: +bias+Res[map(row)] -> fp32 (proj)
template <int MODE>
__global__ __launch_bounds__(256)
void gemm_bt(const bf16_t* __restrict__ A, const bf16_t* __restrict__ Bt,
             const float* __restrict__ bias,
             bf16_t* Cbf, float* Cf, const float* Res,
             int M, int N, int K, int nblk) {
  __shared__ __align__(16) bf16_t As[128 * 32];
  __shared__ __align__(16) bf16_t Bs[128 * 32];
  const int tid = threadIdx.x;
  const int lane = tid & 63;
  const int wave = tid >> 6;
  const int wm = wave & 1, wn = wave >> 1;
  const int bid = blockIdx.x;
  const int m_idx = bid / nblk;
  const int n_idx = bid - m_idx * nblk;
  const int m0 = m_idx * 128;
  const int n0 = n_idx * 128;

  f32x4 acc[4][4];
#pragma unroll
  for (int i = 0; i < 4; i++)
#pragma unroll
    for (int j = 0; j < 4; j++) acc[i][j] = f32x4{0.f, 0.f, 0.f, 0.f};

  const bf16_t* Ag = A + (size_t)m0 * K;
  const bf16_t* Bg = Bt + (size_t)n0 * K;
  const int lr = lane & 15;
  const int kq = (lane >> 4) * 8;

  for (int k0 = 0; k0 < K; k0 += 32) {
#pragma unroll
    for (int it = 0; it < 2; it++) {
      int slot = it * 256 + tid;
      int row = slot >> 2;
      int ko = (slot & 3) << 3;
      bf16_t* ldsA = As + (it * 256 + wave * 64) * 8;
      bf16_t* ldsB = Bs + (it * 256 + wave * 64) * 8;
      gload_lds16(Ag + (size_t)row * K + k0 + ko, ldsA);
      gload_lds16(Bg + (size_t)row * K + k0 + ko, ldsB);
    }
    __syncthreads();
    bf16x8 af[4], bfr[4];
#pragma unroll
    for (int i = 0; i < 4; i++) {
      af[i]  = *(const bf16x8*)(As + (wm * 64 + i * 16 + lr) * 32 + kq);
      bfr[i] = *(const bf16x8*)(Bs + (wn * 64 + i * 16 + lr) * 32 + kq);
    }
#pragma unroll
    for (int i = 0; i < 4; i++)
#pragma unroll
      for (int j = 0; j < 4; j++)
        acc[i][j] = __builtin_amdgcn_mfma_f32_16x16x32_bf16(af[i], bfr[j], acc[i][j], 0, 0, 0);
    __syncthreads();
  }

  const int quad = lane >> 4;
#pragma unroll
  for (int i = 0; i < 4; i++) {
    int rbase = m0 + wm * 64 + i * 16 + quad * 4;
#pragma unroll
    for (int j = 0; j < 4; j++) {
      int col = n0 + wn * 64 + j * 16 + lr;
      float bi = bias[col];
#pragma unroll
      for (int r = 0; r < 4; r++) {
        int row = rbase + r;
        float v = acc[i][j][r] + bi;
        if (MODE == 0) {
          Cbf[(size_t)row * N + col] = (bf16_t)v;
        } else {
          int w = row / 49, t = row - w * 49;
          int img = w >> 6, wi = w & 63;
          int wr = wi >> 3, wc = wi & 7;
          int rr = t / 7, cc = t - rr * 7;
          int h = wr * 7 + rr + 3; if (h >= 56) h -= 56;
          int ww2 = wc * 7 + cc + 3; if (ww2 >= 56) ww2 -= 56;
          size_t idx = ((size_t)img * 3136 + h * 56 + ww2) * 256 + col;
          Cf[idx] = v + Res[idx];
        }
      }
    }
  }
}

// ---------------- MFMA attention: one block (4 waves) per (window, head) --
__global__ __launch_bounds__(256)
void attn_mfma(const bf16_t* __restrict__ qkv, const float* __restrict__ bm,
               bf16_t* __restrict__ o) {
  __shared__ __align__(16) bf16_t Ps[64 * 72];
  __shared__ __align__(16) bf16_t Vt[32 * 72];
  const int w = blockIdx.x, h = blockIdx.y;
  const int tid = threadIdx.x;
  const int lane = tid & 63, wv = tid >> 6;
  const int lr = lane & 15, quad = lane >> 4;
  const int wi = w & 63;
  const int mtype = (((wi >> 3) == 7) ? 2 : 0) | (((wi & 7) == 7) ? 1 : 0);
  const bf16_t* base = qkv + (size_t)w * 49 * 768 + h * 32;

  bf16x8 zero8;
#pragma unroll
  for (int z = 0; z < 8; z++) zero8[z] = (bf16_t)0.f;

  {
    int tok = tid >> 2, d8 = (tid & 3) * 8;
    bf16x8 v8 = zero8;
    if (tok < 49) v8 = *(const bf16x8*)(base + (size_t)tok * 768 + 512 + d8);
#pragma unroll
    for (int z = 0; z < 8; z++) Vt[(d8 + z) * 72 + tok] = v8[z];
  }
  __syncthreads();

  const int mrow = 16 * wv + lr;
  bf16x8 aq = zero8;
  if (mrow < 49) aq = *(const bf16x8*)(base + (size_t)mrow * 768 + quad * 8);
  f32x4 s[4];
#pragma unroll
  for (int j = 0; j < 4; j++) {
    int nrow = 16 * j + lr;
    bf16x8 bk = zero8;
    if (nrow < 49) bk = *(const bf16x8*)(base + (size_t)nrow * 768 + 256 + quad * 8);
    s[j] = __builtin_amdgcn_mfma_f32_16x16x32_bf16(aq, bk, f32x4{0.f, 0.f, 0.f, 0.f}, 0, 0, 0);
  }

  const float* bmb = bm + ((size_t)(mtype * 8 + h) * 64 + 16 * wv) * 64;
  float inv[4];
#pragma unroll
  for (int reg = 0; reg < 4; reg++) {
    int rl = quad * 4 + reg;
    float v0[4];
    float mx = -1e30f;
#pragma unroll
    for (int j = 0; j < 4; j++) {
      float v = s[j][reg] * 0.17677669529663689f + bmb[rl * 64 + 16 * j + lr];
      v0[j] = v;
      mx = fmaxf(mx, v);
    }
#pragma unroll
    for (int off = 8; off > 0; off >>= 1) mx = fmaxf(mx, __shfl_xor(mx, off));
    float sum = 0.f;
#pragma unroll
    for (int j = 0; j < 4; j++) {
      float e = __expf(v0[j] - mx);
      v0[j] = e;
      sum += e;
    }
#pragma unroll
    for (int off = 8; off > 0; off >>= 1) sum += __shfl_xor(sum, off);
    inv[reg] = 1.0f / sum;
#pragma unroll
    for (int j = 0; j < 4; j++)
      Ps[(16 * wv + rl) * 72 + 16 * j + lr] = (bf16_t)v0[j];
  }

  f32x4 oacc[2];
  oacc[0] = f32x4{0.f, 0.f, 0.f, 0.f};
  oacc[1] = f32x4{0.f, 0.f, 0.f, 0.f};
#pragma unroll
  for (int kk = 0; kk < 2; kk++) {
    bf16x8 ap = *(const bf16x8*)(Ps + (16 * wv + lr) * 72 + kk * 32 + quad * 8);
#pragma unroll
    for (int n = 0; n < 2; n++) {
      bf16x8 bv = *(const bf16x8*)(Vt + (16 * n + lr) * 72 + kk * 32 + quad * 8);
      oacc[n] = __builtin_amdgcn_mfma_f32_16x16x32_bf16(ap, bv, oacc[n], 0, 0, 0);
    }
  }
#pragma unroll
  for (int n = 0; n < 2; n++) {
#pragma unroll
    for (int reg = 0; reg < 4; reg++) {
      int row = 16 * wv + quad * 4 + reg;
      if (row < 49) {
        int d = 16 * n + lr;
        o[((size_t)w * 49 + row) * 256 + h * 32 + d] = (bf16_t)(oacc[n][reg] * inv[reg]);
      }
    }
  }
}

// ---------------- FUSED MLP: out += fc2(gelu(fc1(y2))) --------------------
// R4: no LDS A-slab. A-frags (y2) loaded global->VGPR per k-step (block's
// 32KB slab is L2-resident across the 8 hc re-reads). LDS = Ws 16K + Hs 17.4K
// = 33.4 KB -> 4 blocks/CU by LDS; __launch_bounds__(256,3) caps regs for
// 3 waves/EU. Waves 2x2: wr = row-half (32 rows), wc = col-half.
__global__ __launch_bounds__(256, 3)
void fused_mlp(const bf16_t* __restrict__ y2, const bf16_t* __restrict__ W1t,
               const float* __restrict__ b1, const bf16_t* __restrict__ W2t,
               const float* __restrict__ b2, float* __restrict__ out) {
  __shared__ __align__(16) bf16_t Ws[8192];       // 16 KB W staging
  __shared__ __align__(16) bf16_t Hs[64 * 136];   // 17.4 KB H chunk
  const int tid = threadIdx.x;
  const int lane = tid & 63, wave = tid >> 6;
  const int lr = lane & 15, quad = lane >> 4;
  const int wr = wave & 1, wc = wave >> 1;
  const int m0 = blockIdx.x * 64;
  const bf16_t* Arow0 = y2 + (size_t)(m0 + 32 * wr + lr) * 256;       // i=0 row
  const bf16_t* Arow1 = y2 + (size_t)(m0 + 32 * wr + 16 + lr) * 256;  // i=1 row

  f32x4 acc2[2][8];
#pragma unroll
  for (int i = 0; i < 2; i++)
#pragma unroll
    for (int n = 0; n < 8; n++) acc2[i][n] = f32x4{0.f, 0.f, 0.f, 0.f};

  for (int hc = 0; hc < 8; hc++) {
    // ---- phase A: H[64, 128] = y2[64,256] @ W1t[hc*128 .. +128]^T
    f32x4 acc1[2][4];
#pragma unroll
    for (int i = 0; i < 2; i++)
#pragma unroll
      for (int j = 0; j < 4; j++) acc1[i][j] = f32x4{0.f, 0.f, 0.f, 0.f};

    for (int ks = 0; ks < 4; ks++) {          // kstep 64 over K=256
      __syncthreads();                         // Ws safe to overwrite
#pragma unroll
      for (int r = 0; r < 4; r++) {            // stage [2 kk-subtiles][128][32]
        int sub = r >> 1, half = r & 1;
        int row = half * 64 + (tid >> 2), k8 = tid & 3;
        const bf16_t* src = W1t + (size_t)(hc * 128 + row) * 256 + ks * 64 + sub * 32 + k8 * 8;
        gload_lds16(src, Ws + sub * 4096 + half * 2048 + wave * 512);
      }
      // A-frags straight from global (L2-hit after first pass)
      bf16x8 a[2][2];
#pragma unroll
      for (int kk = 0; kk < 2; kk++) {
        a[kk][0] = *(const bf16x8*)(Arow0 + ks * 64 + kk * 32 + quad * 8);
        a[kk][1] = *(const bf16x8*)(Arow1 + ks * 64 + kk * 32 + quad * 8);
      }
      __syncthreads();                         // staged ready
#pragma unroll
      for (int kk = 0; kk < 2; kk++) {
        bf16x8 b[4];
#pragma unroll
        for (int j = 0; j < 4; j++)
          b[j] = *(const bf16x8*)(Ws + kk * 4096 + (64 * wc + 16 * j + lr) * 32 + quad * 8);
#pragma unroll
        for (int i = 0; i < 2; i++)
#pragma unroll
          for (int j = 0; j < 4; j++)
            acc1[i][j] = __builtin_amdgcn_mfma_f32_16x16x32_bf16(a[kk][i], b[j], acc1[i][j], 0, 0, 0);
      }
    }
    // GELU (tanh approx) + write Hs [row][col], stride 136 (2-way free)
#pragma unroll
    for (int i = 0; i < 2; i++) {
#pragma unroll
      for (int j = 0; j < 4; j++) {
        float bias1 = b1[hc * 128 + 64 * wc + 16 * j + lr];
        int hcol = 64 * wc + 16 * j + lr;
#pragma unroll
        for (int reg = 0; reg < 4; reg++) {
          int row_l = 32 * wr + 16 * i + quad * 4 + reg;
          float v = acc1[i][j][reg] + bias1;
          float arg = fminf(v * (0.7978845608f + 0.0356774081f * v * v), 15.f);
          float e = __expf(2.f * arg);
          float g = v * (e / (e + 1.f));
          Hs[row_l * 136 + hcol] = (bf16_t)g;
        }
      }
    }
    // ---- phase B: acc2 += Hs @ W2t[:, hc*128 .. +128]^T
    for (int ks2 = 0; ks2 < 4; ks2++) {       // kstep 32 over chunk k=128
      __syncthreads();                         // Hs writes done / Ws safe
#pragma unroll
      for (int r = 0; r < 4; r++) {            // stage W2t [256][32]
        int row = r * 64 + (tid >> 2), k8 = tid & 3;
        const bf16_t* src = W2t + (size_t)row * 1024 + hc * 128 + ks2 * 32 + k8 * 8;
        gload_lds16(src, Ws + r * 2048 + wave * 512);
      }
      __syncthreads();
      bf16x8 ah[2], bw[8];
#pragma unroll
      for (int i = 0; i < 2; i++)
        ah[i] = *(const bf16x8*)(Hs + (32 * wr + 16 * i + lr) * 136 + ks2 * 32 + quad * 8);
#pragma unroll
      for (int n = 0; n < 8; n++)
        bw[n] = *(const bf16x8*)(Ws + (128 * wc + 16 * n + lr) * 32 + quad * 8);
#pragma unroll
      for (int i = 0; i < 2; i++)
#pragma unroll
        for (int n = 0; n < 8; n++)
          acc2[i][n] = __builtin_amdgcn_mfma_f32_16x16x32_bf16(ah[i], bw[n], acc2[i][n], 0, 0, 0);
    }
  }

  // epilogue: out += acc2 + b2
#pragma unroll
  for (int i = 0; i < 2; i++) {
#pragma unroll
    for (int n = 0; n < 8; n++) {
      int col = 128 * wc + 16 * n + lr;
      float bi = b2[col];
#pragma unroll
      for (int reg = 0; reg < 4; reg++) {
        int row = m0 + 32 * wr + 16 * i + quad * 4 + reg;
        size_t idx = (size_t)row * 256 + col;
        out[idx] = acc2[i][n][reg] + bi + out[idx];
      }
    }
  }
}

// ---------------- launcher ------------------------------------------------
extern "C" void kernel_launch(void* const* d_in, const int* in_sizes, int n_in,
                              void* d_out, int out_size, void* d_ws, size_t ws_size,
                              hipStream_t stream) {
  const float* x      = (const float*)d_in[0];
  const float* g1     = (const float*)d_in[1];
  const float* b1     = (const float*)d_in[2];
  const float* qkv_w  = (const float*)d_in[3];
  const float* qkv_b  = (const float*)d_in[4];
  const float* proj_w = (const float*)d_in[5];
  const float* proj_b = (const float*)d_in[6];
  const float* rpb    = (const float*)d_in[7];
  const float* g2     = (const float*)d_in[8];
  const float* b2     = (const float*)d_in[9];
  const float* fc1_w  = (const float*)d_in[10];
  const float* fc1_b  = (const float*)d_in[11];
  const float* fc2_w  = (const float*)d_in[12];
  const float* fc2_b  = (const float*)d_in[13];
  float* out = (float*)d_out;
  char* ws = (char*)d_ws;

  bf16_t* xw   = (bf16_t*)ws;                  // [0,51.4M) LN1 out, later y2
  bf16_t* qkv  = (bf16_t*)(ws + 51380224);     // [51.4,205.5M)
  bf16_t* ow   = (bf16_t*)(ws + 205520896);    // [205.5,256.9M)
  bf16_t* y2   = xw;
  bf16_t* qkvWt  = (bf16_t*)(ws + 256901120);
  bf16_t* projWt = qkvWt + 768 * 256;
  bf16_t* fc1Wt  = projWt + 256 * 256;
  bf16_t* fc2Wt  = fc1Wt + 1024 * 256;         // 512 KB, time-shared with bm
  float*  bm     = (float*)fc2Wt;

  transpose_cast3<<<dim3(1024, 3), 256, 0, stream>>>(qkv_w, proj_w, fc1_w,
                                                     qkvWt, projWt, fc1Wt);
  build_bm<<<dim3(4, 8), 256, 0, stream>>>(rpb, bm);

  ln_cast<<<25088, 256, 0, stream>>>(x, g1, b1, xw, 1);
  gemm_bt<0><<<784 * 6, 256, 0, stream>>>(xw, qkvWt, qkv_b, qkv, nullptr, nullptr,
                                          100352, 768, 256, 6);
  attn_mfma<<<dim3(2048, 8), 256, 0, stream>>>(qkv, bm, ow);
  // bm dead -> transpose fc2 into its region
  transpose_cast<<<(256 * 1024 + 255) / 256, 256, 0, stream>>>(fc2_w, fc2Wt, 1024, 256);
  gemm_bt<3><<<784 * 2, 256, 0, stream>>>(ow, projWt, proj_b, nullptr, out, x,
                                          100352, 256, 256, 2);
  ln_cast<<<25088, 256, 0, stream>>>(out, g2, b2, y2, 0);
  fused_mlp<<<1568, 256, 0, stream>>>(y2, fc1Wt, fc1_b, fc2Wt, fc2_b, out);
}

// Round 5
// 767.704 us; speedup vs baseline: 1.0797x; 1.0797x over previous
//
#include <hip/hip_runtime.h>
#include <hip/hip_bf16.h>
#include <math.h>

// Swin block: LN1 -> shift+window -> QKV -> MFMA attn -> proj(+reverse+res)
//             -> LN2 -> FUSED MLP (fc1+GELU+fc2+res, h never touches HBM)
// R5: fused_mlp v3 — wave-owned 16-row strips, A-frags resident in VGPRs
//     (y2 read once, no LDS slab, no L2 re-read), 49 KB LDS -> 3 blocks/CU,
//     wave-local H handoff (barriers only for 32 KB weight staging).

typedef __bf16 bf16_t;
typedef __bf16 bf16x4 __attribute__((ext_vector_type(4)));
typedef __bf16 bf16x8 __attribute__((ext_vector_type(8)));
typedef float f32x4 __attribute__((ext_vector_type(4)));

#define AS1 __attribute__((address_space(1)))
#define AS3 __attribute__((address_space(3)))

__device__ __forceinline__ void gload_lds16(const bf16_t* g, bf16_t* l) {
  __builtin_amdgcn_global_load_lds((AS1 void*)g, (AS3 void*)l, 16, 0, 0);
}

// ---------------- weight transpose + cast (3 K=256 weights in one grid) ---
__global__ void transpose_cast3(const float* __restrict__ qkv_w,
                                const float* __restrict__ proj_w,
                                const float* __restrict__ fc1_w,
                                bf16_t* __restrict__ qkvWt,
                                bf16_t* __restrict__ projWt,
                                bf16_t* __restrict__ fc1Wt) {
  int idx = blockIdx.x * 256 + threadIdx.x;
  const float* w;
  bf16_t* wt;
  int N;
  if (blockIdx.y == 0) { w = qkv_w; wt = qkvWt; N = 768; }
  else if (blockIdx.y == 1) { w = proj_w; wt = projWt; N = 256; }
  else { w = fc1_w; wt = fc1Wt; N = 1024; }
  if (idx < N * 256) {
    int n = idx >> 8, k = idx & 255;
    wt[idx] = (bf16_t)w[(size_t)k * N + n];
  }
}

__global__ void transpose_cast(const float* __restrict__ w, bf16_t* __restrict__ wt,
                               int K, int N) {
  int idx = blockIdx.x * 256 + threadIdx.x;
  if (idx < N * K) {
    int n = idx / K, k = idx - n * K;
    wt[idx] = (bf16_t)w[(size_t)k * N + n];
  }
}

// ---------------- bias+mask table: bm[type][head][64][64] fp32 -----------
__global__ void build_bm(const float* __restrict__ rpb, float* __restrict__ bm) {
  int t = blockIdx.x, h = blockIdx.y;
  int wr = (t & 2) ? 7 : 0, wc = (t & 1) ? 7 : 0;
  for (int e = threadIdx.x; e < 4096; e += 256) {
    int r = e >> 6, c = e & 63;
    float v;
    if (c >= 49) {
      v = -30000.f;
    } else if (r >= 49) {
      v = 0.f;
    } else {
      int r1 = r / 7, c1 = r - r1 * 7;
      int r2 = c / 7, c2 = c - r2 * 7;
      v = rpb[((r1 - r2 + 6) * 13 + (c1 - c2 + 6)) * 8 + h];
      int hp = wr * 7 + r1, wp = wc * 7 + c1;
      int hq = wr * 7 + r2, wq = wc * 7 + c2;
      int ri = (hp < 49 ? 0 : (hp < 53 ? 1 : 2)) * 3 + (wp < 49 ? 0 : (wp < 53 ? 1 : 2));
      int rj = (hq < 49 ? 0 : (hq < 53 ? 1 : 2)) * 3 + (wq < 49 ? 0 : (wq < 53 ? 1 : 2));
      if (ri != rj) v -= 100.f;
    }
    bm[((size_t)(t * 8 + h) * 64 + r) * 64 + c] = v;
  }
}

// ---------------- LayerNorm (+ optional shift/window gather) -> bf16 ------
__global__ __launch_bounds__(256)
void ln_cast(const float* __restrict__ src, const float* __restrict__ gamma,
             const float* __restrict__ beta, bf16_t* __restrict__ dst, int windowed) {
  int row = blockIdx.x * 4 + (threadIdx.x >> 6);
  int lane = threadIdx.x & 63;
  size_t srow;
  if (windowed) {
    int w = row / 49, t = row - w * 49;
    int img = w >> 6, wi = w & 63;
    int wr = wi >> 3, wc = wi & 7;
    int rr = t / 7, cc = t - rr * 7;
    int h = wr * 7 + rr + 3; if (h >= 56) h -= 56;
    int ww = wc * 7 + cc + 3; if (ww >= 56) ww -= 56;
    srow = (size_t)img * 3136 + h * 56 + ww;
  } else {
    srow = row;
  }
  float4 v = *(const float4*)(src + srow * 256 + lane * 4);
  float s = v.x + v.y + v.z + v.w;
  float s2 = v.x * v.x + v.y * v.y + v.z * v.z + v.w * v.w;
#pragma unroll
  for (int off = 32; off > 0; off >>= 1) {
    s += __shfl_xor(s, off);
    s2 += __shfl_xor(s2, off);
  }
  float mu = s * (1.0f / 256.0f);
  float rs = rsqrtf(s2 * (1.0f / 256.0f) - mu * mu + 1e-5f);
  float4 g = *(const float4*)(gamma + lane * 4);
  float4 b = *(const float4*)(beta + lane * 4);
  bf16x4 o;
  o[0] = (bf16_t)((v.x - mu) * rs * g.x + b.x);
  o[1] = (bf16_t)((v.y - mu) * rs * g.y + b.y);
  o[2] = (bf16_t)((v.z - mu) * rs * g.z + b.z);
  o[3] = (bf16_t)((v.w - mu) * rs * g.w + b.w);
  *(bf16x4*)(dst + (size_t)row * 256 + lane * 4) = o;
}

// ---------------- GEMM: C[M,N] = A[M,K] * Bt[N,K]^T -----------------------
// 1-D grid, n-major within m: consecutive blocks share the A-tile (L2 reuse).
// MODE 0: +bias -> bf16 (QKV)   MODE 3: +bias+Res[map(row)] -> fp32 (proj)
template <int MODE>
__global__ __launch_bounds__(256)
void gemm_bt(const bf16_t* __restrict__ A, const bf16_t* __restrict__ Bt,
             const float* __restrict__ bias,
             bf16_t* Cbf, float* Cf, const float* Res,
             int M, int N, int K, int nblk) {
  __shared__ __align__(16) bf16_t As[128 * 32];
  __shared__ __align__(16) bf16_t Bs[128 * 32];
  const int tid = threadIdx.x;
  const int lane = tid & 63;
  const int wave = tid >> 6;
  const int wm = wave & 1, wn = wave >> 1;
  const int bid = blockIdx.x;
  const int m_idx = bid / nblk;
  const int n_idx = bid - m_idx * nblk;
  const int m0 = m_idx * 128;
  const int n0 = n_idx * 128;

  f32x4 acc[4][4];
#pragma unroll
  for (int i = 0; i < 4; i++)
#pragma unroll
    for (int j = 0; j < 4; j++) acc[i][j] = f32x4{0.f, 0.f, 0.f, 0.f};

  const bf16_t* Ag = A + (size_t)m0 * K;
  const bf16_t* Bg = Bt + (size_t)n0 * K;
  const int lr = lane & 15;
  const int kq = (lane >> 4) * 8;

  for (int k0 = 0; k0 < K; k0 += 32) {
#pragma unroll
    for (int it = 0; it < 2; it++) {
      int slot = it * 256 + tid;
      int row = slot >> 2;
      int ko = (slot & 3) << 3;
      bf16_t* ldsA = As + (it * 256 + wave * 64) * 8;
      bf16_t* ldsB = Bs + (it * 256 + wave * 64) * 8;
      gload_lds16(Ag + (size_t)row * K + k0 + ko, ldsA);
      gload_lds16(Bg + (size_t)row * K + k0 + ko, ldsB);
    }
    __syncthreads();
    bf16x8 af[4], bfr[4];
#pragma unroll
    for (int i = 0; i < 4; i++) {
      af[i]  = *(const bf16x8*)(As + (wm * 64 + i * 16 + lr) * 32 + kq);
      bfr[i] = *(const bf16x8*)(Bs + (wn * 64 + i * 16 + lr) * 32 + kq);
    }
#pragma unroll
    for (int i = 0; i < 4; i++)
#pragma unroll
      for (int j = 0; j < 4; j++)
        acc[i][j] = __builtin_amdgcn_mfma_f32_16x16x32_bf16(af[i], bfr[j], acc[i][j], 0, 0, 0);
    __syncthreads();
  }

  const int quad = lane >> 4;
#pragma unroll
  for (int i = 0; i < 4; i++) {
    int rbase = m0 + wm * 64 + i * 16 + quad * 4;
#pragma unroll
    for (int j = 0; j < 4; j++) {
      int col = n0 + wn * 64 + j * 16 + lr;
      float bi = bias[col];
#pragma unroll
      for (int r = 0; r < 4; r++) {
        int row = rbase + r;
        float v = acc[i][j][r] + bi;
        if (MODE == 0) {
          Cbf[(size_t)row * N + col] = (bf16_t)v;
        } else {
          int w = row / 49, t = row - w * 49;
          int img = w >> 6, wi = w & 63;
          int wr = wi >> 3, wc = wi & 7;
          int rr = t / 7, cc = t - rr * 7;
          int h = wr * 7 + rr + 3; if (h >= 56) h -= 56;
          int ww2 = wc * 7 + cc + 3; if (ww2 >= 56) ww2 -= 56;
          size_t idx = ((size_t)img * 3136 + h * 56 + ww2) * 256 + col;
          Cf[idx] = v + Res[idx];
        }
      }
    }
  }
}

// ---------------- MFMA attention: one block (4 waves) per (window, head) --
__global__ __launch_bounds__(256)
void attn_mfma(const bf16_t* __restrict__ qkv, const float* __restrict__ bm,
               bf16_t* __restrict__ o) {
  __shared__ __align__(16) bf16_t Ps[64 * 72];
  __shared__ __align__(16) bf16_t Vt[32 * 72];
  const int w = blockIdx.x, h = blockIdx.y;
  const int tid = threadIdx.x;
  const int lane = tid & 63, wv = tid >> 6;
  const int lr = lane & 15, quad = lane >> 4;
  const int wi = w & 63;
  const int mtype = (((wi >> 3) == 7) ? 2 : 0) | (((wi & 7) == 7) ? 1 : 0);
  const bf16_t* base = qkv + (size_t)w * 49 * 768 + h * 32;

  bf16x8 zero8;
#pragma unroll
  for (int z = 0; z < 8; z++) zero8[z] = (bf16_t)0.f;

  {
    int tok = tid >> 2, d8 = (tid & 3) * 8;
    bf16x8 v8 = zero8;
    if (tok < 49) v8 = *(const bf16x8*)(base + (size_t)tok * 768 + 512 + d8);
#pragma unroll
    for (int z = 0; z < 8; z++) Vt[(d8 + z) * 72 + tok] = v8[z];
  }
  __syncthreads();

  const int mrow = 16 * wv + lr;
  bf16x8 aq = zero8;
  if (mrow < 49) aq = *(const bf16x8*)(base + (size_t)mrow * 768 + quad * 8);
  f32x4 s[4];
#pragma unroll
  for (int j = 0; j < 4; j++) {
    int nrow = 16 * j + lr;
    bf16x8 bk = zero8;
    if (nrow < 49) bk = *(const bf16x8*)(base + (size_t)nrow * 768 + 256 + quad * 8);
    s[j] = __builtin_amdgcn_mfma_f32_16x16x32_bf16(aq, bk, f32x4{0.f, 0.f, 0.f, 0.f}, 0, 0, 0);
  }

  const float* bmb = bm + ((size_t)(mtype * 8 + h) * 64 + 16 * wv) * 64;
  float inv[4];
#pragma unroll
  for (int reg = 0; reg < 4; reg++) {
    int rl = quad * 4 + reg;
    float v0[4];
    float mx = -1e30f;
#pragma unroll
    for (int j = 0; j < 4; j++) {
      float v = s[j][reg] * 0.17677669529663689f + bmb[rl * 64 + 16 * j + lr];
      v0[j] = v;
      mx = fmaxf(mx, v);
    }
#pragma unroll
    for (int off = 8; off > 0; off >>= 1) mx = fmaxf(mx, __shfl_xor(mx, off));
    float sum = 0.f;
#pragma unroll
    for (int j = 0; j < 4; j++) {
      float e = __expf(v0[j] - mx);
      v0[j] = e;
      sum += e;
    }
#pragma unroll
    for (int off = 8; off > 0; off >>= 1) sum += __shfl_xor(sum, off);
    inv[reg] = 1.0f / sum;
#pragma unroll
    for (int j = 0; j < 4; j++)
      Ps[(16 * wv + rl) * 72 + 16 * j + lr] = (bf16_t)v0[j];
  }

  f32x4 oacc[2];
  oacc[0] = f32x4{0.f, 0.f, 0.f, 0.f};
  oacc[1] = f32x4{0.f, 0.f, 0.f, 0.f};
#pragma unroll
  for (int kk = 0; kk < 2; kk++) {
    bf16x8 ap = *(const bf16x8*)(Ps + (16 * wv + lr) * 72 + kk * 32 + quad * 8);
#pragma unroll
    for (int n = 0; n < 2; n++) {
      bf16x8 bv = *(const bf16x8*)(Vt + (16 * n + lr) * 72 + kk * 32 + quad * 8);
      oacc[n] = __builtin_amdgcn_mfma_f32_16x16x32_bf16(ap, bv, oacc[n], 0, 0, 0);
    }
  }
#pragma unroll
  for (int n = 0; n < 2; n++) {
#pragma unroll
    for (int reg = 0; reg < 4; reg++) {
      int row = 16 * wv + quad * 4 + reg;
      if (row < 49) {
        int d = 16 * n + lr;
        o[((size_t)w * 49 + row) * 256 + h * 32 + d] = (bf16_t)(oacc[n][reg] * inv[reg]);
      }
    }
  }
}

// ---------------- FUSED MLP v3: out += fc2(gelu(fc1(y2))) -----------------
// Wave owns rows [m0+16w, m0+16w+16). A-frags (y2, K=256) resident in 32
// VGPRs, loaded once. Per hidden chunk hc (128): phase A (2 k-steps of 128,
// Ws 32KB staged, 32 MFMA each) -> GELU -> wave-local Hs strip -> phase B
// (2 k-steps of 64 over hidden, Ws 32KB, 32 MFMA each). Barriers only guard
// Ws. LDS 49KB -> 3 blocks/CU; VGPR capped for 3 waves/EU -> 12 waves/CU.
__global__ __launch_bounds__(256, 3)
void fused_mlp(const bf16_t* __restrict__ y2, const bf16_t* __restrict__ W1t,
               const float* __restrict__ b1, const bf16_t* __restrict__ W2t,
               const float* __restrict__ b2, float* __restrict__ out) {
  __shared__ __align__(16) bf16_t Ws[16384];        // 32 KB weight staging
  __shared__ __align__(16) bf16_t Hs[4 * 16 * 136]; // 17 KB, per-wave strips
  const int tid = threadIdx.x;
  const int lane = tid & 63, wave = tid >> 6;
  const int lr = lane & 15, quad = lane >> 4;
  const int m0 = blockIdx.x * 64;
  bf16_t* HsW = Hs + wave * (16 * 136);

  // resident A-frags: row = m0+16*wave+lr, k = ks*128 + kk*32 + quad*8
  const bf16_t* Arow = y2 + (size_t)(m0 + 16 * wave + lr) * 256;
  bf16x8 aF[2][4];
#pragma unroll
  for (int ks = 0; ks < 2; ks++)
#pragma unroll
    for (int kk = 0; kk < 4; kk++)
      aF[ks][kk] = *(const bf16x8*)(Arow + ks * 128 + kk * 32 + quad * 8);

  f32x4 acc2[16];
#pragma unroll
  for (int n = 0; n < 16; n++) acc2[n] = f32x4{0.f, 0.f, 0.f, 0.f};

  for (int hc = 0; hc < 8; hc++) {
    // ---- phase A: H[16w..+16, 128] = y2 @ W1t[hc*128..+128]^T
    f32x4 acc1[8];
#pragma unroll
    for (int j = 0; j < 8; j++) acc1[j] = f32x4{0.f, 0.f, 0.f, 0.f};

    for (int ks = 0; ks < 2; ks++) {
      __syncthreads();                       // all waves done reading Ws
#pragma unroll
      for (int kk = 0; kk < 4; kk++) {       // stage 128 rows x 128 k (32 KB)
#pragma unroll
        for (int it = 0; it < 2; it++) {
          int row = it * 64 + wave * 16 + (lane >> 2);
          int k8 = lane & 3;
          const bf16_t* src = W1t + (size_t)(hc * 128 + row) * 256
                              + ks * 128 + kk * 32 + k8 * 8;
          gload_lds16(src, Ws + kk * 4096 + (it * 64 + wave * 16) * 32);
        }
      }
      __syncthreads();                       // staged data visible
#pragma unroll
      for (int kk = 0; kk < 4; kk++) {
#pragma unroll
        for (int j = 0; j < 8; j++) {
          bf16x8 b = *(const bf16x8*)(Ws + kk * 4096 + (16 * j + lr) * 32 + quad * 8);
          acc1[j] = __builtin_amdgcn_mfma_f32_16x16x32_bf16(aF[ks][kk], b, acc1[j], 0, 0, 0);
        }
      }
    }
    // GELU (exact, erf) -> wave-local Hs strip [16 rows][128 cols] stride 136
#pragma unroll
    for (int j = 0; j < 8; j++) {
      float bias1 = b1[hc * 128 + 16 * j + lr];
#pragma unroll
      for (int reg = 0; reg < 4; reg++) {
        float v = acc1[j][reg] + bias1;
        v = 0.5f * v * (1.0f + erff(v * 0.70710678118654752f));
        HsW[(4 * quad + reg) * 136 + 16 * j + lr] = (bf16_t)v;
      }
    }
    // ---- phase B: acc2 += H @ W2t[:, hc*128..+128]^T
    for (int ks2 = 0; ks2 < 2; ks2++) {
      __syncthreads();                       // Ws reads done (also fences Hs)
#pragma unroll
      for (int kk = 0; kk < 2; kk++) {       // stage 256 rows x 64 k (32 KB)
#pragma unroll
        for (int it = 0; it < 4; it++) {
          int row = it * 64 + wave * 16 + (lane >> 2);
          int k8 = lane & 3;
          const bf16_t* src = W2t + (size_t)row * 1024
                              + hc * 128 + ks2 * 64 + kk * 32 + k8 * 8;
          gload_lds16(src, Ws + kk * 8192 + (it * 64 + wave * 16) * 32);
        }
      }
      __syncthreads();
#pragma unroll
      for (int kk = 0; kk < 2; kk++) {
        bf16x8 ah = *(const bf16x8*)(HsW + lr * 136 + ks2 * 64 + kk * 32 + quad * 8);
#pragma unroll
        for (int n = 0; n < 16; n++) {
          bf16x8 bw = *(const bf16x8*)(Ws + kk * 8192 + (16 * n + lr) * 32 + quad * 8);
          acc2[n] = __builtin_amdgcn_mfma_f32_16x16x32_bf16(ah, bw, acc2[n], 0, 0, 0);
        }
      }
    }
  }

  // epilogue: out += acc2 + b2 (rows 16*wave + 4*quad + reg, cols 16n+lr)
#pragma unroll
  for (int n = 0; n < 16; n++) {
    int col = 16 * n + lr;
    float bi = b2[col];
#pragma unroll
    for (int reg = 0; reg < 4; reg++) {
      int row = m0 + 16 * wave + 4 * quad + reg;
      size_t idx = (size_t)row * 256 + col;
      out[idx] = acc2[n][reg] + bi + out[idx];
    }
  }
}

// ---------------- launcher ------------------------------------------------
extern "C" void kernel_launch(void* const* d_in, const int* in_sizes, int n_in,
                              void* d_out, int out_size, void* d_ws, size_t ws_size,
                              hipStream_t stream) {
  const float* x      = (const float*)d_in[0];
  const float* g1     = (const float*)d_in[1];
  const float* b1     = (const float*)d_in[2];
  const float* qkv_w  = (const float*)d_in[3];
  const float* qkv_b  = (const float*)d_in[4];
  const float* proj_w = (const float*)d_in[5];
  const float* proj_b = (const float*)d_in[6];
  const float* rpb    = (const float*)d_in[7];
  const float* g2     = (const float*)d_in[8];
  const float* b2     = (const float*)d_in[9];
  const float* fc1_w  = (const float*)d_in[10];
  const float* fc1_b  = (const float*)d_in[11];
  const float* fc2_w  = (const float*)d_in[12];
  const float* fc2_b  = (const float*)d_in[13];
  float* out = (float*)d_out;
  char* ws = (char*)d_ws;

  bf16_t* xw   = (bf16_t*)ws;                  // [0,51.4M) LN1 out, later y2
  bf16_t* qkv  = (bf16_t*)(ws + 51380224);     // [51.4,205.5M)
  bf16_t* ow   = (bf16_t*)(ws + 205520896);    // [205.5,256.9M)
  bf16_t* y2   = xw;
  bf16_t* qkvWt  = (bf16_t*)(ws + 256901120);
  bf16_t* projWt = qkvWt + 768 * 256;
  bf16_t* fc1Wt  = projWt + 256 * 256;
  bf16_t* fc2Wt  = fc1Wt + 1024 * 256;         // 512 KB, time-shared with bm
  float*  bm     = (float*)fc2Wt;

  transpose_cast3<<<dim3(1024, 3), 256, 0, stream>>>(qkv_w, proj_w, fc1_w,
                                                     qkvWt, projWt, fc1Wt);
  build_bm<<<dim3(4, 8), 256, 0, stream>>>(rpb, bm);

  ln_cast<<<25088, 256, 0, stream>>>(x, g1, b1, xw, 1);
  gemm_bt<0><<<784 * 6, 256, 0, stream>>>(xw, qkvWt, qkv_b, qkv, nullptr, nullptr,
                                          100352, 768, 256, 6);
  attn_mfma<<<dim3(2048, 8), 256, 0, stream>>>(qkv, bm, ow);
  // bm dead -> transpose fc2 into its region
  transpose_cast<<<(256 * 1024 + 255) / 256, 256, 0, stream>>>(fc2_w, fc2Wt, 1024, 256);
  gemm_bt<3><<<784 * 2, 256, 0, stream>>>(ow, projWt, proj_b, nullptr, out, x,
                                          100352, 256, 256, 2);
  ln_cast<<<25088, 256, 0, stream>>>(out, g2, b2, y2, 0);
  fused_mlp<<<1568, 256, 0, stream>>>(y2, fc1Wt, fc1_b, fc2Wt, fc2_b, out);
}